// Round 1
// baseline (1883.245 us; speedup 1.0000x reference)
//
#include <hip/hip_runtime.h>
#include <math.h>

// Problem dims (fixed by setup_inputs)
constexpr int Bn = 128;   // batch
constexpr int Tn = 512;   // time steps
constexpr int Jn = 700;   // input features
constexpr int Hn = 512;   // hidden
constexpr int On = 20;    // output classes
constexpr int Mn = Bn * Tn;   // 65536 rows

// ---------------------------------------------------------------------------
// GEMM: C[M x N] = A[M x K] * W[N x K]^T   (A row-major K-contig, W row-major
// K-contig -> "NT" layout, both loads coalesced). fp32 SIMD baseline.
// BM=128, BN=64, BK=16, 256 threads, 8x4 per thread.
// ---------------------------------------------------------------------------
template <int BM, int BN, int BK>
__global__ __launch_bounds__(256) void gemm_nt(const float* __restrict__ A,
                                               const float* __restrict__ W,
                                               float* __restrict__ C,
                                               int M, int N, int K) {
    __shared__ float As[BK][BM + 4];   // +4 keeps 16B alignment of rows
    __shared__ float Bs[BK][BN + 4];

    const int tid = threadIdx.x;
    const int bm = blockIdx.x * BM;
    const int bn = blockIdx.y * BN;

    const int tx = tid % 16;  // 16 col-groups * 4 cols = 64
    const int ty = tid / 16;  // 16 row-groups * 8 rows = 128

    float acc[8][4] = {};

    const int arow = tid / 4;        // 0..63
    const int acol = (tid % 4) * 4;  // 0,4,8,12

    const int ktiles = (K + BK - 1) / BK;
    for (int kt = 0; kt < ktiles; ++kt) {
        const int k0 = kt * BK;
        // ---- stage A tile (128x16) : 2 float4 per thread ----
#pragma unroll
        for (int rr = 0; rr < 2; ++rr) {
            const int m = bm + arow + rr * 64;
            const int k = k0 + acol;
            float4 v = make_float4(0.f, 0.f, 0.f, 0.f);
            if (m < M) {
                if (k + 3 < K) {
                    v = *(const float4*)(A + (size_t)m * K + k);
                } else {
                    float t0 = (k + 0 < K) ? A[(size_t)m * K + k + 0] : 0.f;
                    float t1 = (k + 1 < K) ? A[(size_t)m * K + k + 1] : 0.f;
                    float t2 = (k + 2 < K) ? A[(size_t)m * K + k + 2] : 0.f;
                    float t3 = (k + 3 < K) ? A[(size_t)m * K + k + 3] : 0.f;
                    v = make_float4(t0, t1, t2, t3);
                }
            }
            As[acol + 0][arow + rr * 64] = v.x;
            As[acol + 1][arow + rr * 64] = v.y;
            As[acol + 2][arow + rr * 64] = v.z;
            As[acol + 3][arow + rr * 64] = v.w;
        }
        // ---- stage W tile (64x16) : 1 float4 per thread ----
        {
            const int n = bn + arow;
            const int k = k0 + acol;
            float4 v = make_float4(0.f, 0.f, 0.f, 0.f);
            if (n < N) {
                if (k + 3 < K) {
                    v = *(const float4*)(W + (size_t)n * K + k);
                } else {
                    float t0 = (k + 0 < K) ? W[(size_t)n * K + k + 0] : 0.f;
                    float t1 = (k + 1 < K) ? W[(size_t)n * K + k + 1] : 0.f;
                    float t2 = (k + 2 < K) ? W[(size_t)n * K + k + 2] : 0.f;
                    float t3 = (k + 3 < K) ? W[(size_t)n * K + k + 3] : 0.f;
                    v = make_float4(t0, t1, t2, t3);
                }
            }
            Bs[acol + 0][arow] = v.x;
            Bs[acol + 1][arow] = v.y;
            Bs[acol + 2][arow] = v.z;
            Bs[acol + 3][arow] = v.w;
        }
        __syncthreads();
#pragma unroll
        for (int kk = 0; kk < BK; ++kk) {
            float a[8], b[4];
#pragma unroll
            for (int r = 0; r < 8; ++r) a[r] = As[kk][ty * 8 + r];
#pragma unroll
            for (int c = 0; c < 4; ++c) b[c] = Bs[kk][tx * 4 + c];
#pragma unroll
            for (int r = 0; r < 8; ++r)
#pragma unroll
                for (int c = 0; c < 4; ++c) acc[r][c] += a[r] * b[c];
        }
        __syncthreads();
    }

#pragma unroll
    for (int r = 0; r < 8; ++r) {
        const int m = bm + ty * 8 + r;
        if (m >= M) continue;
#pragma unroll
        for (int c = 0; c < 4; ++c) {
            const int n = bn + tx * 4 + c;
            if (n < N) C[(size_t)m * N + n] = acc[r][c];
        }
    }
}

// ---------------------------------------------------------------------------
// Per-channel sum / sum-of-squares over M rows of X[M x N].
// grid.x blocks each own a contiguous row chunk; coalesced column-parallel
// reads; one atomicAdd per (block, channel).
// ---------------------------------------------------------------------------
__global__ __launch_bounds__(256) void stats_kernel(const float* __restrict__ X,
                                                    float* __restrict__ sums,
                                                    float* __restrict__ sumsq,
                                                    int M, int N) {
    const int nchunks = gridDim.x;
    const int rows_per = (M + nchunks - 1) / nchunks;
    const int r0 = blockIdx.x * rows_per;
    const int r1 = min(M, r0 + rows_per);
    for (int i = threadIdx.x; i < N; i += blockDim.x) {
        float s = 0.f, q = 0.f;
        for (int r = r0; r < r1; ++r) {
            float v = X[(size_t)r * N + i];
            s += v;
            q += v * v;
        }
        atomicAdd(&sums[i], s);
        atomicAdd(&sumsq[i], q);
    }
}

// ---------------------------------------------------------------------------
// LIF scan (layers 1 & 2): BN-normalize + sequential membrane update + spike.
// One thread per (b, i); reads X[(b*T+t)*N + i], writes spikes to S_out.
// X != S_out (no aliasing) so restrict allows load batching across the
// sequential U-chain.
// ---------------------------------------------------------------------------
__global__ __launch_bounds__(256) void lif_scan(const float* __restrict__ X,
                                                float* __restrict__ S_out,
                                                const float* __restrict__ sums,
                                                const float* __restrict__ sumsq,
                                                const float* __restrict__ beta_raw,
                                                const float* __restrict__ gamma,
                                                const float* __restrict__ bias,
                                                int B, int T, int N) {
    const int gid = blockIdx.x * blockDim.x + threadIdx.x;
    if (gid >= B * N) return;
    const int b = gid / N;
    const int i = gid % N;

    const float invM = 1.f / (float)(B * T);
    const float mean = sums[i] * invM;
    const float var = sumsq[i] * invM - mean * mean;
    const float inv = rsqrtf(var + 1e-5f);
    const float g = gamma[i] * inv;
    const float bi = bias[i] - mean * g;
    const float beta = 1.f / (1.f + expf(-beta_raw[i]));
    const float omb = 1.f - beta;

    const float* xp = X + (size_t)b * T * N + i;
    float* sp = S_out + (size_t)b * T * N + i;

    float U = 0.f, Sp = 0.f;
#pragma unroll 8
    for (int t = 0; t < T; ++t) {
        const float xt = xp[(size_t)t * N] * g + bi;
        U = beta * (U - Sp) + omb * xt;
        Sp = (U > 1.0f) ? 1.0f : 0.0f;
        sp[(size_t)t * N] = Sp;
    }
}

// ---------------------------------------------------------------------------
// Readout: BN + linear EMA scan + softmax over 20 classes + sum over T.
// One block per batch element. Scan done in LDS (T x O tile = 40 KB).
// ---------------------------------------------------------------------------
__global__ __launch_bounds__(256) void readout_kernel(const float* __restrict__ A,
                                                      const float* __restrict__ sums,
                                                      const float* __restrict__ sumsq,
                                                      const float* __restrict__ beta_raw,
                                                      const float* __restrict__ gamma,
                                                      const float* __restrict__ bias,
                                                      float* __restrict__ out) {
    __shared__ float xs[Tn * On];
    __shared__ float gsh[On], bsh[On], betash[On];
    __shared__ float red[4][On];

    const int b = blockIdx.x;
    const int tid = threadIdx.x;

    if (tid < On) {
        const float invM = 1.f / (float)Mn;
        const float mean = sums[tid] * invM;
        const float var = sumsq[tid] * invM - mean * mean;
        const float inv = rsqrtf(var + 1e-5f);
        const float g = gamma[tid] * inv;
        gsh[tid] = g;
        bsh[tid] = bias[tid] - mean * g;
        betash[tid] = 1.f / (1.f + expf(-beta_raw[tid]));
    }
    __syncthreads();

    const float* Ab = A + (size_t)b * Tn * On;
    for (int idx = tid; idx < Tn * On; idx += 256) {
        const int o = idx % On;
        xs[idx] = Ab[idx] * gsh[o] + bsh[o];
    }
    __syncthreads();

    if (tid < On) {
        const float beta = betash[tid], omb = 1.f - beta;
        float U = 0.f;
        for (int t = 0; t < Tn; ++t) {
            U = beta * U + omb * xs[t * On + tid];
            xs[t * On + tid] = U;
        }
    }
    __syncthreads();

    float part[On];
#pragma unroll
    for (int o = 0; o < On; ++o) part[o] = 0.f;

    for (int t = tid; t < Tn; t += 256) {
        float v[On];
        float m = -1e30f;
#pragma unroll
        for (int o = 0; o < On; ++o) {
            v[o] = xs[t * On + o];
            m = fmaxf(m, v[o]);
        }
        float s = 0.f;
#pragma unroll
        for (int o = 0; o < On; ++o) {
            v[o] = expf(v[o] - m);
            s += v[o];
        }
        const float rs = 1.f / s;
#pragma unroll
        for (int o = 0; o < On; ++o) part[o] += v[o] * rs;
    }

#pragma unroll
    for (int o = 0; o < On; ++o) {
#pragma unroll
        for (int off = 32; off > 0; off >>= 1) part[o] += __shfl_down(part[o], off);
    }
    const int lane = tid & 63, wid = tid >> 6;
    if (lane == 0) {
#pragma unroll
        for (int o = 0; o < On; ++o) red[wid][o] = part[o];
    }
    __syncthreads();
    if (tid < On) out[b * On + tid] = red[0][tid] + red[1][tid] + red[2][tid] + red[3][tid];
}

// ---------------------------------------------------------------------------
extern "C" void kernel_launch(void* const* d_in, const int* in_sizes, int n_in,
                              void* d_out, int out_size, void* d_ws, size_t ws_size,
                              hipStream_t stream) {
    const float* x   = (const float*)d_in[0];
    const float* W1  = (const float*)d_in[1];
    const float* be1 = (const float*)d_in[2];
    const float* g1  = (const float*)d_in[3];
    const float* b1  = (const float*)d_in[4];
    const float* W2  = (const float*)d_in[5];
    const float* be2 = (const float*)d_in[6];
    const float* g2  = (const float*)d_in[7];
    const float* b2  = (const float*)d_in[8];
    const float* Wr  = (const float*)d_in[9];
    const float* ber = (const float*)d_in[10];
    const float* gr  = (const float*)d_in[11];
    const float* br  = (const float*)d_in[12];
    float* out = (float*)d_out;

    char* ws = (char*)d_ws;
    const size_t bufBytes = (size_t)Mn * Hn * sizeof(float);  // 134 MB
    float* buf1 = (float*)ws;
    float* buf2 = (float*)(ws + bufBytes);
    float* stats = (float*)(ws + 2 * bufBytes);
    float* s1 = stats;
    float* q1 = s1 + Hn;
    float* s2 = q1 + Hn;
    float* q2 = s2 + Hn;
    float* s3 = q2 + Hn;
    float* q3 = s3 + On;

    hipMemsetAsync(stats, 0, (4 * Hn + 2 * On) * sizeof(float), stream);

    // Layer 1: x[M x J] * W1[H x J]^T -> buf1
    gemm_nt<128, 64, 16><<<dim3(Mn / 128, Hn / 64), 256, 0, stream>>>(x, W1, buf1, Mn, Hn, Jn);
    stats_kernel<<<256, 256, 0, stream>>>(buf1, s1, q1, Mn, Hn);
    lif_scan<<<(Bn * Hn) / 256, 256, 0, stream>>>(buf1, buf2, s1, q1, be1, g1, b1, Bn, Tn, Hn);

    // Layer 2: spk[M x H] * W2[H x H]^T -> buf1
    gemm_nt<128, 64, 16><<<dim3(Mn / 128, Hn / 64), 256, 0, stream>>>(buf2, W2, buf1, Mn, Hn, Hn);
    stats_kernel<<<256, 256, 0, stream>>>(buf1, s2, q2, Mn, Hn);
    lif_scan<<<(Bn * Hn) / 256, 256, 0, stream>>>(buf1, buf2, s2, q2, be2, g2, b2, Bn, Tn, Hn);

    // Readout: spk[M x H] * Wr[O x H]^T -> buf1 (as [M x O])
    gemm_nt<128, 64, 16><<<dim3(Mn / 128, 1), 256, 0, stream>>>(buf2, Wr, buf1, Mn, On, Hn);
    stats_kernel<<<256, 256, 0, stream>>>(buf1, s3, q3, Mn, On);
    readout_kernel<<<Bn, 256, 0, stream>>>(buf1, s3, q3, ber, gr, br, out);
}

// Round 2
// 1189.275 us; speedup vs baseline: 1.5835x; 1.5835x over previous
//
#include <hip/hip_runtime.h>
#include <math.h>

typedef __bf16 bf16_t;
typedef __bf16 bf16x4 __attribute__((ext_vector_type(4)));
typedef __bf16 bf16x8 __attribute__((ext_vector_type(8)));
typedef float f32x4 __attribute__((ext_vector_type(4)));

// Problem dims (fixed by setup_inputs)
constexpr int Bn = 128;   // batch
constexpr int Tn = 512;   // time steps
constexpr int Jn = 700;   // input features
constexpr int Hn = 512;   // hidden
constexpr int On = 20;    // output classes
constexpr int Mn = Bn * Tn;   // 65536 rows

// MFMA GEMM tile config
constexpr int BM = 128;
constexpr int BN = 128;
constexpr int BK = 32;
constexpr int LST = 40;   // LDS row stride in bf16 elems (32 padded to 40 -> 80B rows,
                          // 16B-aligned for ds_read_b128, <=2-way bank aliasing = free)

// ---------------------------------------------------------------------------
// C[M x N] = A[M x K] * W[N x K]^T via bf16 MFMA with fp32-accuracy splitting.
// SPLIT_A=true : A fp32 -> (Ahi + Alo) bf16; 3 passes hi*hi + hi*lo + lo*hi.
// SPLIT_A=false: A already-exact bf16 (spikes in {0,1}); W split; 2 passes.
// All passes accumulate into the same fp32 accumulator.
// 256 threads = 4 waves in 2x2; each wave does a 64x64 region = 4x4 MFMA tiles.
// ---------------------------------------------------------------------------
template <bool SPLIT_A>
__global__ __launch_bounds__(256, 2) void gemm_mfma(
    const void* __restrict__ Av, const float* __restrict__ Wp,
    float* __restrict__ C, int M, int N, int K)
{
    constexpr int ASZ = BM * LST;
    __shared__ __align__(16) bf16_t sAhi[ASZ];
    __shared__ __align__(16) bf16_t sAlo[SPLIT_A ? ASZ : 8];
    __shared__ __align__(16) bf16_t sWhi[BN * LST];
    __shared__ __align__(16) bf16_t sWlo[BN * LST];

    const int tid = threadIdx.x;
    const int bm = blockIdx.x * BM;
    const int bn = blockIdx.y * BN;

    const int lane = tid & 63;
    const int wv   = tid >> 6;
    const int wm   = (wv & 1) * 64;
    const int wn   = (wv >> 1) * 64;
    const int fr   = lane & 15;   // row/col within 16x16 tile
    const int quad = lane >> 4;   // 0..3
    const int koff = quad * 8;    // k-offset of this lane's 8-elem fragment

    const f32x4 zero4 = {0.f, 0.f, 0.f, 0.f};
    f32x4 acc[4][4];
#pragma unroll
    for (int i = 0; i < 4; ++i)
#pragma unroll
        for (int j = 0; j < 4; ++j) acc[i][j] = zero4;

    const int ktiles = (K + BK - 1) / BK;
    for (int kt = 0; kt < ktiles; ++kt) {
        const int k0 = kt * BK;

        // ---- stage W tile (BN x BK), split hi/lo ----
        {
            const int r = tid >> 3;        // 0..31
            const int c = (tid & 7) * 4;   // 0,4,...,28
#pragma unroll
            for (int rr = 0; rr < 4; ++rr) {
                const int row = r + rr * 32;
                const int n = bn + row;
                const int gk = k0 + c;
                float4 v = make_float4(0.f, 0.f, 0.f, 0.f);
                if (n < N && gk < K) v = *(const float4*)(Wp + (size_t)n * K + gk);
                bf16x4 hv, lv;
                const float* pv = &v.x;
#pragma unroll
                for (int q = 0; q < 4; ++q) {
                    const float f = pv[q];
                    const bf16_t h = (bf16_t)f;
                    hv[q] = h;
                    lv[q] = (bf16_t)(f - (float)h);
                }
                *(bf16x4*)&sWhi[row * LST + c] = hv;
                *(bf16x4*)&sWlo[row * LST + c] = lv;
            }
        }
        // ---- stage A tile (BM x BK) ----
        if (SPLIT_A) {
            const float* A = (const float*)Av;
            const int r = tid >> 3;
            const int c = (tid & 7) * 4;
#pragma unroll
            for (int rr = 0; rr < 4; ++rr) {
                const int row = r + rr * 32;
                const int gk = k0 + c;
                float4 v = make_float4(0.f, 0.f, 0.f, 0.f);
                if (gk < K) v = *(const float4*)(A + (size_t)(bm + row) * K + gk);
                bf16x4 hv, lv;
                const float* pv = &v.x;
#pragma unroll
                for (int q = 0; q < 4; ++q) {
                    const float f = pv[q];
                    const bf16_t h = (bf16_t)f;
                    hv[q] = h;
                    lv[q] = (bf16_t)(f - (float)h);
                }
                *(bf16x4*)&sAhi[row * LST + c] = hv;
                *(bf16x4*)&sAlo[row * LST + c] = lv;
            }
        } else {
            // A is bf16 (exact spike values); K is a multiple of 32 here (512).
            const bf16_t* A = (const bf16_t*)Av;
            const int r = tid >> 2;        // 0..63
            const int c = (tid & 3) * 8;   // 0,8,16,24
#pragma unroll
            for (int rr = 0; rr < 2; ++rr) {
                const int row = r + rr * 64;
                const bf16x8 v = *(const bf16x8*)(A + (size_t)(bm + row) * K + k0 + c);
                *(bf16x8*)&sAhi[row * LST + c] = v;
            }
        }
        __syncthreads();

        // ---- fragment loads + MFMA ----
        bf16x8 ah[4], wh[4], wl[4];
#pragma unroll
        for (int i = 0; i < 4; ++i) {
            ah[i] = *(const bf16x8*)&sAhi[(wm + i * 16 + fr) * LST + koff];
            wh[i] = *(const bf16x8*)&sWhi[(wn + i * 16 + fr) * LST + koff];
            wl[i] = *(const bf16x8*)&sWlo[(wn + i * 16 + fr) * LST + koff];
        }
        if (SPLIT_A) {
            bf16x8 al[4];
#pragma unroll
            for (int i = 0; i < 4; ++i)
                al[i] = *(const bf16x8*)&sAlo[(wm + i * 16 + fr) * LST + koff];
#pragma unroll
            for (int i = 0; i < 4; ++i)
#pragma unroll
                for (int j = 0; j < 4; ++j) {
                    acc[i][j] = __builtin_amdgcn_mfma_f32_16x16x32_bf16(ah[i], wh[j], acc[i][j], 0, 0, 0);
                    acc[i][j] = __builtin_amdgcn_mfma_f32_16x16x32_bf16(ah[i], wl[j], acc[i][j], 0, 0, 0);
                    acc[i][j] = __builtin_amdgcn_mfma_f32_16x16x32_bf16(al[i], wh[j], acc[i][j], 0, 0, 0);
                }
        } else {
#pragma unroll
            for (int i = 0; i < 4; ++i)
#pragma unroll
                for (int j = 0; j < 4; ++j) {
                    acc[i][j] = __builtin_amdgcn_mfma_f32_16x16x32_bf16(ah[i], wh[j], acc[i][j], 0, 0, 0);
                    acc[i][j] = __builtin_amdgcn_mfma_f32_16x16x32_bf16(ah[i], wl[j], acc[i][j], 0, 0, 0);
                }
        }
        __syncthreads();
    }

    // ---- epilogue: C/D layout col=lane&15, row=quad*4+reg ----
#pragma unroll
    for (int i = 0; i < 4; ++i) {
#pragma unroll
        for (int j = 0; j < 4; ++j) {
            const int col = bn + wn + j * 16 + fr;
            if (col >= N) continue;
#pragma unroll
            for (int rg = 0; rg < 4; ++rg) {
                const int row = bm + wm + i * 16 + quad * 4 + rg;
                C[(size_t)row * N + col] = acc[i][j][rg];
            }
        }
    }
}

// ---------------------------------------------------------------------------
// Per-channel sum / sum-of-squares over M rows of X[M x N].
// ---------------------------------------------------------------------------
__global__ __launch_bounds__(256) void stats_kernel(const float* __restrict__ X,
                                                    float* __restrict__ sums,
                                                    float* __restrict__ sumsq,
                                                    int M, int N) {
    const int nchunks = gridDim.x;
    const int rows_per = (M + nchunks - 1) / nchunks;
    const int r0 = blockIdx.x * rows_per;
    const int r1 = min(M, r0 + rows_per);
    for (int i = threadIdx.x; i < N; i += blockDim.x) {
        float s = 0.f, q = 0.f;
        for (int r = r0; r < r1; ++r) {
            float v = X[(size_t)r * N + i];
            s += v;
            q += v * v;
        }
        atomicAdd(&sums[i], s);
        atomicAdd(&sumsq[i], q);
    }
}

// ---------------------------------------------------------------------------
// LIF scan: BN-normalize + sequential membrane update + spike.
// Spikes written as bf16 (exact: values are 0.0 / 1.0) for the next MFMA GEMM.
// ---------------------------------------------------------------------------
__global__ __launch_bounds__(256) void lif_scan(const float* __restrict__ X,
                                                bf16_t* __restrict__ S_out,
                                                const float* __restrict__ sums,
                                                const float* __restrict__ sumsq,
                                                const float* __restrict__ beta_raw,
                                                const float* __restrict__ gamma,
                                                const float* __restrict__ bias,
                                                int B, int T, int N) {
    const int gid = blockIdx.x * blockDim.x + threadIdx.x;
    if (gid >= B * N) return;
    const int b = gid / N;
    const int i = gid % N;

    const float invM = 1.f / (float)(B * T);
    const float mean = sums[i] * invM;
    const float var = sumsq[i] * invM - mean * mean;
    const float inv = rsqrtf(var + 1e-5f);
    const float g = gamma[i] * inv;
    const float bi = bias[i] - mean * g;
    const float beta = 1.f / (1.f + expf(-beta_raw[i]));
    const float omb = 1.f - beta;

    const float* xp = X + (size_t)b * T * N + i;
    bf16_t* sp = S_out + (size_t)b * T * N + i;

    float U = 0.f, Sp = 0.f;
#pragma unroll 8
    for (int t = 0; t < T; ++t) {
        const float xt = xp[(size_t)t * N] * g + bi;
        U = beta * (U - Sp) + omb * xt;
        Sp = (U > 1.0f) ? 1.0f : 0.0f;
        sp[(size_t)t * N] = (bf16_t)Sp;
    }
}

// ---------------------------------------------------------------------------
// Readout: BN + linear EMA scan + softmax over 20 classes + sum over T.
// ---------------------------------------------------------------------------
__global__ __launch_bounds__(256) void readout_kernel(const float* __restrict__ A,
                                                      const float* __restrict__ sums,
                                                      const float* __restrict__ sumsq,
                                                      const float* __restrict__ beta_raw,
                                                      const float* __restrict__ gamma,
                                                      const float* __restrict__ bias,
                                                      float* __restrict__ out) {
    __shared__ float xs[Tn * On];
    __shared__ float gsh[On], bsh[On], betash[On];
    __shared__ float red[4][On];

    const int b = blockIdx.x;
    const int tid = threadIdx.x;

    if (tid < On) {
        const float invM = 1.f / (float)Mn;
        const float mean = sums[tid] * invM;
        const float var = sumsq[tid] * invM - mean * mean;
        const float inv = rsqrtf(var + 1e-5f);
        const float g = gamma[tid] * inv;
        gsh[tid] = g;
        bsh[tid] = bias[tid] - mean * g;
        betash[tid] = 1.f / (1.f + expf(-beta_raw[tid]));
    }
    __syncthreads();

    const float* Ab = A + (size_t)b * Tn * On;
    for (int idx = tid; idx < Tn * On; idx += 256) {
        const int o = idx % On;
        xs[idx] = Ab[idx] * gsh[o] + bsh[o];
    }
    __syncthreads();

    if (tid < On) {
        const float beta = betash[tid], omb = 1.f - beta;
        float U = 0.f;
        for (int t = 0; t < Tn; ++t) {
            U = beta * U + omb * xs[t * On + tid];
            xs[t * On + tid] = U;
        }
    }
    __syncthreads();

    float part[On];
#pragma unroll
    for (int o = 0; o < On; ++o) part[o] = 0.f;

    for (int t = tid; t < Tn; t += 256) {
        float v[On];
        float m = -1e30f;
#pragma unroll
        for (int o = 0; o < On; ++o) {
            v[o] = xs[t * On + o];
            m = fmaxf(m, v[o]);
        }
        float s = 0.f;
#pragma unroll
        for (int o = 0; o < On; ++o) {
            v[o] = expf(v[o] - m);
            s += v[o];
        }
        const float rs = 1.f / s;
#pragma unroll
        for (int o = 0; o < On; ++o) part[o] += v[o] * rs;
    }

#pragma unroll
    for (int o = 0; o < On; ++o) {
#pragma unroll
        for (int off = 32; off > 0; off >>= 1) part[o] += __shfl_down(part[o], off);
    }
    const int lane = tid & 63, wid = tid >> 6;
    if (lane == 0) {
#pragma unroll
        for (int o = 0; o < On; ++o) red[wid][o] = part[o];
    }
    __syncthreads();
    if (tid < On) out[b * On + tid] = red[0][tid] + red[1][tid] + red[2][tid] + red[3][tid];
}

// ---------------------------------------------------------------------------
extern "C" void kernel_launch(void* const* d_in, const int* in_sizes, int n_in,
                              void* d_out, int out_size, void* d_ws, size_t ws_size,
                              hipStream_t stream) {
    const float* x   = (const float*)d_in[0];
    const float* W1  = (const float*)d_in[1];
    const float* be1 = (const float*)d_in[2];
    const float* g1  = (const float*)d_in[3];
    const float* b1  = (const float*)d_in[4];
    const float* W2  = (const float*)d_in[5];
    const float* be2 = (const float*)d_in[6];
    const float* g2  = (const float*)d_in[7];
    const float* b2  = (const float*)d_in[8];
    const float* Wr  = (const float*)d_in[9];
    const float* ber = (const float*)d_in[10];
    const float* gr  = (const float*)d_in[11];
    const float* br  = (const float*)d_in[12];
    float* out = (float*)d_out;

    char* ws = (char*)d_ws;
    const size_t buf1Bytes = (size_t)Mn * Hn * sizeof(float);    // 134 MB fp32 pre-acts
    const size_t bufSBytes = (size_t)Mn * Hn * sizeof(bf16_t);   // 67 MB bf16 spikes
    const size_t bufRBytes = (size_t)Mn * On * sizeof(float);    // 5.2 MB readout pre-acts
    float*  buf1 = (float*)ws;
    bf16_t* bufS = (bf16_t*)(ws + buf1Bytes);
    float*  bufR = (float*)(ws + buf1Bytes + bufSBytes);
    float*  stats = (float*)(ws + buf1Bytes + bufSBytes + bufRBytes);
    float* s1 = stats;
    float* q1 = s1 + Hn;
    float* s2 = q1 + Hn;
    float* q2 = s2 + Hn;
    float* s3 = q2 + Hn;
    float* q3 = s3 + On;

    hipMemsetAsync(stats, 0, (4 * Hn + 2 * On) * sizeof(float), stream);

    // Layer 1: x[M x J](fp32, split3) * W1[H x J]^T -> buf1
    gemm_mfma<true><<<dim3(Mn / BM, Hn / BN), 256, 0, stream>>>(x, W1, buf1, Mn, Hn, Jn);
    stats_kernel<<<256, 256, 0, stream>>>(buf1, s1, q1, Mn, Hn);
    lif_scan<<<(Bn * Hn) / 256, 256, 0, stream>>>(buf1, bufS, s1, q1, be1, g1, b1, Bn, Tn, Hn);

    // Layer 2: spikes[M x H](bf16 exact) * W2[H x H]^T(split2) -> buf1
    gemm_mfma<false><<<dim3(Mn / BM, Hn / BN), 256, 0, stream>>>(bufS, W2, buf1, Mn, Hn, Hn);
    stats_kernel<<<256, 256, 0, stream>>>(buf1, s2, q2, Mn, Hn);
    lif_scan<<<(Bn * Hn) / 256, 256, 0, stream>>>(buf1, bufS, s2, q2, be2, g2, b2, Bn, Tn, Hn);

    // Readout: spikes[M x H](bf16) * Wr[O x H]^T(split2) -> bufR [M x O]
    gemm_mfma<false><<<dim3(Mn / BM, 1), 256, 0, stream>>>(bufS, Wr, bufR, Mn, On, Hn);
    stats_kernel<<<256, 256, 0, stream>>>(bufR, s3, q3, Mn, On);
    readout_kernel<<<Bn, 256, 0, stream>>>(bufR, s3, q3, ber, gr, br, out);
}

// Round 3
// 777.230 us; speedup vs baseline: 2.4230x; 1.5301x over previous
//
#include <hip/hip_runtime.h>
#include <math.h>

typedef _Float16 f16_t;
typedef _Float16 f16x8 __attribute__((ext_vector_type(8)));
typedef float f32x4 __attribute__((ext_vector_type(4)));

// Problem dims (fixed by setup_inputs)
constexpr int Bn = 128;       // batch
constexpr int Tn = 512;       // time steps
constexpr int Jn = 700;       // input features
constexpr int Jp = 704;       // padded to BK multiple
constexpr int Hn = 512;       // hidden
constexpr int On = 20;        // output classes
constexpr int Mn = Bn * Tn;   // 65536 rows

#define LDS_U32(p) ((__attribute__((address_space(3))) uint32_t*)(p))
#define GLB_U32(p) ((const __attribute__((address_space(1))) uint32_t*)(p))

// ---------------------------------------------------------------------------
// m97-style fp16 MFMA GEMM: C[M x Nout] = (A[M x LDA] * W[NP x LDW]^T) * outScale
// K-dim iterates pairs p (32 elems each) x halves h (hi/lo planes):
//   kA = h*APLANE + p*32   (APLANE==0 -> A has no lo plane, reuse LDS tile)
//   kW = h*WPLANE + p*32
// 128x128 tile, 4 waves (2x2), 16x16x32 MFMA, global_load_lds staging,
// unpadded 64B LDS rows (conflict-free fragment reads, required by lds-dma).
// Epilogue scales, stores C, and atomically accumulates per-channel BN stats.
// ---------------------------------------------------------------------------
__global__ __launch_bounds__(256, 3) void gemm_m97(
    const f16_t* __restrict__ A, const f16_t* __restrict__ W,
    float* __restrict__ C, float* __restrict__ s_out, float* __restrict__ q_out,
    int LDA, int APLANE, int LDW, int WPLANE, int pairs, int Nout, float outScale)
{
    __shared__ __align__(16) f16_t sA[128 * 32];
    __shared__ __align__(16) f16_t sW[128 * 32];

    const int tid  = threadIdx.x;
    const int bm   = blockIdx.y * 128;
    const int bn   = blockIdx.x * 128;
    const int lane = tid & 63;
    const int wv   = tid >> 6;
    const int wm   = (wv & 1) * 64;
    const int wn   = (wv >> 1) * 64;
    const int fr   = lane & 15;
    const int quad = lane >> 4;

    // staging: each wave DMA-loads two 16-row chunks of A and of W per k-tile
    const int srow = lane >> 2;        // 0..15 row within chunk
    const int scol = (lane & 3) * 8;   // f16 elem offset within 32-elem row

    f32x4 acc[4][4];
#pragma unroll
    for (int i = 0; i < 4; ++i)
#pragma unroll
        for (int j = 0; j < 4; ++j) acc[i][j] = {0.f, 0.f, 0.f, 0.f};

    for (int p = 0; p < pairs; ++p) {
#pragma unroll
        for (int h = 0; h < 2; ++h) {
            const int kA = h * APLANE + p * 32;
            const int kW = h * WPLANE + p * 32;
            if (h == 0 || APLANE != 0) {
#pragma unroll
                for (int c = 0; c < 2; ++c) {
                    const int r = wv * 16 + c * 64;
                    const uint32_t aoff = __builtin_amdgcn_readfirstlane(r * 64);
                    const f16_t* gp = A + (size_t)(bm + r + srow) * LDA + kA + scol;
                    __builtin_amdgcn_global_load_lds(GLB_U32(gp),
                                                     LDS_U32((char*)sA + aoff), 16, 0, 0);
                }
            }
#pragma unroll
            for (int c = 0; c < 2; ++c) {
                const int r = wv * 16 + c * 64;
                const uint32_t woff = __builtin_amdgcn_readfirstlane(r * 64);
                const f16_t* gp = W + (size_t)(bn + r + srow) * LDW + kW + scol;
                __builtin_amdgcn_global_load_lds(GLB_U32(gp),
                                                 LDS_U32((char*)sW + woff), 16, 0, 0);
            }
            __syncthreads();

            f16x8 av[4], wvf[4];
#pragma unroll
            for (int i = 0; i < 4; ++i)
                av[i] = *(const f16x8*)&sA[(wm + i * 16 + fr) * 32 + quad * 8];
#pragma unroll
            for (int j = 0; j < 4; ++j)
                wvf[j] = *(const f16x8*)&sW[(wn + j * 16 + fr) * 32 + quad * 8];
#pragma unroll
            for (int i = 0; i < 4; ++i)
#pragma unroll
                for (int j = 0; j < 4; ++j)
                    acc[i][j] = __builtin_amdgcn_mfma_f32_16x16x32_f16(av[i], wvf[j], acc[i][j], 0, 0, 0);
            __syncthreads();
        }
    }

    // ---- epilogue: scale, store C, fused per-channel BN stats ----
#pragma unroll
    for (int j = 0; j < 4; ++j) {
        const int gcol = bn + wn + j * 16 + fr;
        float s = 0.f, q = 0.f;
        if (gcol < Nout) {
#pragma unroll
            for (int i = 0; i < 4; ++i) {
#pragma unroll
                for (int rg = 0; rg < 4; ++rg) {
                    const float v = acc[i][j][rg] * outScale;
                    C[(size_t)(bm + wm + i * 16 + quad * 4 + rg) * Nout + gcol] = v;
                    s += v;
                    q += v * v;
                }
            }
        }
        s += __shfl_xor(s, 16); s += __shfl_xor(s, 32);
        q += __shfl_xor(q, 16); q += __shfl_xor(q, 32);
        if (quad == 0 && gcol < Nout) {
            atomicAdd(&s_out[gcol], s);
            atomicAdd(&q_out[gcol], q);
        }
    }
}

// ---------------------------------------------------------------------------
// x[M x 700] fp32 -> A1[M x 1408] fp16: [hi(32x) | lo], zero-padded 700->704.
// ---------------------------------------------------------------------------
__global__ __launch_bounds__(256) void split_x(const float* __restrict__ x,
                                               f16_t* __restrict__ A1) {
    const int idx = blockIdx.x * 256 + threadIdx.x;
    if (idx >= Mn * Jp) return;
    const int m = idx / Jp, k = idx % Jp;
    const float f = (k < Jn) ? x[(size_t)m * Jn + k] * 32.f : 0.f;
    const f16_t hi = (f16_t)f;
    const f16_t lo = (f16_t)(f - (float)hi);
    A1[(size_t)m * (2 * Jp) + k] = hi;
    A1[(size_t)m * (2 * Jp) + Jp + k] = lo;
}

// ---------------------------------------------------------------------------
// W[N x K] fp32 -> Wo[NP x 2*KP] fp16 [hi(scale*W) | lo], zero pad rows/cols.
// ---------------------------------------------------------------------------
__global__ __launch_bounds__(256) void split_w(const float* __restrict__ Wsrc,
                                               f16_t* __restrict__ Wo,
                                               int N, int K, int KP, int NP, float scale) {
    const int idx = blockIdx.x * 256 + threadIdx.x;
    if (idx >= NP * KP) return;
    const int n = idx / KP, k = idx % KP;
    const float f = (n < N && k < K) ? Wsrc[(size_t)n * K + k] * scale : 0.f;
    const f16_t hi = (f16_t)f;
    const f16_t lo = (f16_t)(f - (float)hi);
    Wo[(size_t)n * (2 * KP) + k] = hi;
    Wo[(size_t)n * (2 * KP) + KP + k] = lo;
}

// ---------------------------------------------------------------------------
// LIF scan: BN-normalize + sequential membrane update + spike (exact f16 out).
// ---------------------------------------------------------------------------
__global__ __launch_bounds__(256) void lif_scan(const float* __restrict__ X,
                                                f16_t* __restrict__ S_out,
                                                const float* __restrict__ sums,
                                                const float* __restrict__ sumsq,
                                                const float* __restrict__ beta_raw,
                                                const float* __restrict__ gamma,
                                                const float* __restrict__ bias,
                                                int B, int T, int N) {
    const int gid = blockIdx.x * blockDim.x + threadIdx.x;
    if (gid >= B * N) return;
    const int b = gid / N;
    const int i = gid % N;

    const float invM = 1.f / (float)(B * T);
    const float mean = sums[i] * invM;
    const float var = sumsq[i] * invM - mean * mean;
    const float inv = rsqrtf(var + 1e-5f);
    const float g = gamma[i] * inv;
    const float bi = bias[i] - mean * g;
    const float beta = 1.f / (1.f + expf(-beta_raw[i]));
    const float omb = 1.f - beta;

    const float* xp = X + (size_t)b * T * N + i;
    f16_t* sp = S_out + (size_t)b * T * N + i;

    float U = 0.f, Sp = 0.f;
#pragma unroll 8
    for (int t = 0; t < T; ++t) {
        const float xt = xp[(size_t)t * N] * g + bi;
        U = beta * (U - Sp) + omb * xt;
        Sp = (U > 1.0f) ? 1.0f : 0.0f;
        sp[(size_t)t * N] = (f16_t)Sp;
    }
}

// ---------------------------------------------------------------------------
// Readout: BN + linear EMA scan + softmax over 20 classes + sum over T.
// ---------------------------------------------------------------------------
__global__ __launch_bounds__(256) void readout_kernel(const float* __restrict__ A,
                                                      const float* __restrict__ sums,
                                                      const float* __restrict__ sumsq,
                                                      const float* __restrict__ beta_raw,
                                                      const float* __restrict__ gamma,
                                                      const float* __restrict__ bias,
                                                      float* __restrict__ out) {
    __shared__ float xs[Tn * On];
    __shared__ float gsh[On], bsh[On], betash[On];
    __shared__ float red[4][On];

    const int b = blockIdx.x;
    const int tid = threadIdx.x;

    if (tid < On) {
        const float invM = 1.f / (float)Mn;
        const float mean = sums[tid] * invM;
        const float var = sumsq[tid] * invM - mean * mean;
        const float inv = rsqrtf(var + 1e-5f);
        const float g = gamma[tid] * inv;
        gsh[tid] = g;
        bsh[tid] = bias[tid] - mean * g;
        betash[tid] = 1.f / (1.f + expf(-beta_raw[tid]));
    }
    __syncthreads();

    const float* Ab = A + (size_t)b * Tn * On;
    for (int idx = tid; idx < Tn * On; idx += 256) {
        const int o = idx % On;
        xs[idx] = Ab[idx] * gsh[o] + bsh[o];
    }
    __syncthreads();

    if (tid < On) {
        const float beta = betash[tid], omb = 1.f - beta;
        float U = 0.f;
        for (int t = 0; t < Tn; ++t) {
            U = beta * U + omb * xs[t * On + tid];
            xs[t * On + tid] = U;
        }
    }
    __syncthreads();

    float part[On];
#pragma unroll
    for (int o = 0; o < On; ++o) part[o] = 0.f;

    for (int t = tid; t < Tn; t += 256) {
        float v[On];
        float m = -1e30f;
#pragma unroll
        for (int o = 0; o < On; ++o) {
            v[o] = xs[t * On + o];
            m = fmaxf(m, v[o]);
        }
        float s = 0.f;
#pragma unroll
        for (int o = 0; o < On; ++o) {
            v[o] = expf(v[o] - m);
            s += v[o];
        }
        const float rs = 1.f / s;
#pragma unroll
        for (int o = 0; o < On; ++o) part[o] += v[o] * rs;
    }

#pragma unroll
    for (int o = 0; o < On; ++o) {
#pragma unroll
        for (int off = 32; off > 0; off >>= 1) part[o] += __shfl_down(part[o], off);
    }
    const int lane = tid & 63, wid = tid >> 6;
    if (lane == 0) {
#pragma unroll
        for (int o = 0; o < On; ++o) red[wid][o] = part[o];
    }
    __syncthreads();
    if (tid < On) out[b * On + tid] = red[0][tid] + red[1][tid] + red[2][tid] + red[3][tid];
}

// ---------------------------------------------------------------------------
extern "C" void kernel_launch(void* const* d_in, const int* in_sizes, int n_in,
                              void* d_out, int out_size, void* d_ws, size_t ws_size,
                              hipStream_t stream) {
    const float* x   = (const float*)d_in[0];
    const float* W1  = (const float*)d_in[1];
    const float* be1 = (const float*)d_in[2];
    const float* g1  = (const float*)d_in[3];
    const float* b1  = (const float*)d_in[4];
    const float* W2  = (const float*)d_in[5];
    const float* be2 = (const float*)d_in[6];
    const float* b2g = (const float*)d_in[7];
    const float* b2  = (const float*)d_in[8];
    const float* Wr  = (const float*)d_in[9];
    const float* ber = (const float*)d_in[10];
    const float* gr  = (const float*)d_in[11];
    const float* br  = (const float*)d_in[12];
    float* out = (float*)d_out;

    char* ws = (char*)d_ws;
    // A1 region (184.5 MB) is dead after GEMM1; bufS (67 MB) reuses it.
    const size_t a1Bytes   = (size_t)Mn * (2 * Jp) * sizeof(f16_t);   // 184.5 MB
    const size_t bufCBytes = (size_t)Mn * Hn * sizeof(float);         // 134 MB
    f16_t* A1   = (f16_t*)ws;
    f16_t* bufS = (f16_t*)ws;                         // overlaps A1 (sequenced)
    float* bufC = (float*)(ws + a1Bytes);
    char*  p    = ws + a1Bytes + bufCBytes;
    float* bufR = (float*)p;              p += (size_t)Mn * On * sizeof(float);
    f16_t* W1s  = (f16_t*)p;              p += (size_t)Hn * (2 * Jp) * sizeof(f16_t);
    f16_t* W2s  = (f16_t*)p;              p += (size_t)Hn * (2 * Hn) * sizeof(f16_t);
    f16_t* Wrs  = (f16_t*)p;              p += (size_t)128 * (2 * Hn) * sizeof(f16_t);
    float* stats = (float*)p;
    float* s1 = stats;       float* q1 = s1 + Hn;
    float* s2 = q1 + Hn;     float* q2 = s2 + Hn;
    float* s3 = q2 + Hn;     float* q3 = s3 + 32;

    hipMemsetAsync(stats, 0, (4 * Hn + 64) * sizeof(float), stream);

    // Pre-split inputs/weights into folded hi|lo fp16 planes (scaled).
    split_x<<<(Mn * Jp + 255) / 256, 256, 0, stream>>>(x, A1);
    split_w<<<(Hn * Jp + 255) / 256, 256, 0, stream>>>(W1, W1s, Hn, Jn, Jp, Hn, 64.f);
    split_w<<<(Hn * Hn + 255) / 256, 256, 0, stream>>>(W2, W2s, Hn, Hn, Hn, Hn, 64.f);
    split_w<<<(128 * Hn + 255) / 256, 256, 0, stream>>>(Wr, Wrs, On, Hn, Hn, 128, 64.f);

    // Layer 1: [xhi|xlo][M x 1408] * [W1hi|W1lo][512 x 1408]^T  (scale 2^-11)
    gemm_m97<<<dim3(4, Mn / 128), 256, 0, stream>>>(A1, W1s, bufC, s1, q1,
        2 * Jp, Jp, 2 * Jp, Jp, Jp / 32, Hn, 1.f / 2048.f);
    lif_scan<<<(Bn * Hn) / 256, 256, 0, stream>>>(bufC, bufS, s1, q1, be1, g1, b1, Bn, Tn, Hn);

    // Layer 2: S[M x 512] * [W2hi|W2lo][512 x 1024]^T  (scale 2^-6)
    gemm_m97<<<dim3(4, Mn / 128), 256, 0, stream>>>(bufS, W2s, bufC, s2, q2,
        Hn, 0, 2 * Hn, Hn, Hn / 32, Hn, 1.f / 64.f);
    lif_scan<<<(Bn * Hn) / 256, 256, 0, stream>>>(bufC, bufS, s2, q2, be2, b2g, b2, Bn, Tn, Hn);

    // Readout: S[M x 512] * [Wrhi|Wrlo][128 x 1024]^T -> [M x 20]  (scale 2^-6)
    gemm_m97<<<dim3(1, Mn / 128), 256, 0, stream>>>(bufS, Wrs, bufR, s3, q3,
        Hn, 0, 2 * Hn, Hn, Hn / 32, On, 1.f / 64.f);
    readout_kernel<<<Bn, 256, 0, stream>>>(bufR, s3, q3, ber, gr, br, out);
}

// Round 4
// 715.893 us; speedup vs baseline: 2.6306x; 1.0857x over previous
//
#include <hip/hip_runtime.h>
#include <math.h>

typedef _Float16 f16_t;
typedef _Float16 f16x4 __attribute__((ext_vector_type(4)));
typedef _Float16 f16x8 __attribute__((ext_vector_type(8)));
typedef float f32x4 __attribute__((ext_vector_type(4)));

// Problem dims (fixed by setup_inputs)
constexpr int Bn = 128;       // batch
constexpr int Tn = 512;       // time steps
constexpr int Jn = 700;       // input features
constexpr int Jp = 704;       // padded to BK multiple
constexpr int Hn = 512;       // hidden
constexpr int On = 20;        // output classes
constexpr int Mn = Bn * Tn;   // 65536 rows

#define LDS_U32(p) ((__attribute__((address_space(3))) uint32_t*)(p))
#define GLB_U32(p) ((const __attribute__((address_space(1))) uint32_t*)(p))

// ---------------------------------------------------------------------------
// N-strip fp16 MFMA GEMM: C[M x Nout] = (A[M x LDA] * W[NP x LDW]^T)*outScale
// NT = 128-wide N-tiles per block (strip). Per k-slice the A-tile is staged
// ONCE and reused against NT W-tiles -> A is read from HBM exactly once
// (round-3 counter showed 520 MB fetch for a 184 MB operand = A-refetch).
// K iterates pairs p (32 elems) x halves h (hi/lo planes):
//   kA = h*APLANE + p*32  (APLANE==0 -> A has no lo plane; LDS tile reused)
//   kW = h*WPLANE + p*32
// 4 waves in 2x2 per 128x128 tile, 16x16x32 MFMA, global_load_lds staging,
// unpadded 64B LDS rows. Epilogue: scale, store, fused BN stats atomics.
// ---------------------------------------------------------------------------
template <int NT>
__global__ __launch_bounds__(256, 2) void gemm_strip(
    const f16_t* __restrict__ A, const f16_t* __restrict__ W,
    float* __restrict__ C, float* __restrict__ s_out, float* __restrict__ q_out,
    int LDA, int APLANE, int LDW, int WPLANE, int pairs, int Nout, float outScale)
{
    __shared__ __align__(16) f16_t sA[128 * 32];
    __shared__ __align__(16) f16_t sW[NT * 128 * 32];

    const int tid  = threadIdx.x;
    const int bm   = blockIdx.y * 128;
    const int bn   = blockIdx.x * (NT * 128);
    const int lane = tid & 63;
    const int wv   = tid >> 6;
    const int wm   = (wv & 1) * 64;
    const int wn   = (wv >> 1) * 64;
    const int fr   = lane & 15;
    const int quad = lane >> 4;

    const int srow = lane >> 2;        // 0..15 row within 16-row chunk
    const int scol = (lane & 3) * 8;   // f16 elem offset within 32-elem row

    f32x4 acc[NT][4][4];
#pragma unroll
    for (int nt = 0; nt < NT; ++nt)
#pragma unroll
        for (int i = 0; i < 4; ++i)
#pragma unroll
            for (int j = 0; j < 4; ++j) acc[nt][i][j] = {0.f, 0.f, 0.f, 0.f};

    for (int p = 0; p < pairs; ++p) {
#pragma unroll
        for (int h = 0; h < 2; ++h) {
            const int kA = h * APLANE + p * 32;
            const int kW = h * WPLANE + p * 32;
            if (h == 0 || APLANE != 0) {
#pragma unroll
                for (int c = 0; c < 2; ++c) {
                    const int r = wv * 16 + c * 64;
                    const uint32_t aoff = __builtin_amdgcn_readfirstlane(r * 64);
                    const f16_t* gp = A + (size_t)(bm + r + srow) * LDA + kA + scol;
                    __builtin_amdgcn_global_load_lds(GLB_U32(gp),
                                                     LDS_U32((char*)sA + aoff), 16, 0, 0);
                }
            }
#pragma unroll
            for (int nt = 0; nt < NT; ++nt) {
#pragma unroll
                for (int c = 0; c < 2; ++c) {
                    const int r = wv * 16 + c * 64;
                    const uint32_t woff = __builtin_amdgcn_readfirstlane(nt * 8192 + r * 64);
                    const f16_t* gp = W + (size_t)(bn + nt * 128 + r + srow) * LDW + kW + scol;
                    __builtin_amdgcn_global_load_lds(GLB_U32(gp),
                                                     LDS_U32((char*)sW + woff), 16, 0, 0);
                }
            }
            __syncthreads();

            f16x8 av[4];
#pragma unroll
            for (int i = 0; i < 4; ++i)
                av[i] = *(const f16x8*)&sA[(wm + i * 16 + fr) * 32 + quad * 8];
#pragma unroll
            for (int nt = 0; nt < NT; ++nt) {
                f16x8 wf[4];
#pragma unroll
                for (int j = 0; j < 4; ++j)
                    wf[j] = *(const f16x8*)&sW[nt * 4096 + (wn + j * 16 + fr) * 32 + quad * 8];
#pragma unroll
                for (int i = 0; i < 4; ++i)
#pragma unroll
                    for (int j = 0; j < 4; ++j)
                        acc[nt][i][j] = __builtin_amdgcn_mfma_f32_16x16x32_f16(av[i], wf[j], acc[nt][i][j], 0, 0, 0);
            }
            __syncthreads();
        }
    }

    // ---- epilogue: scale, store C, fused per-channel BN stats ----
#pragma unroll
    for (int nt = 0; nt < NT; ++nt) {
#pragma unroll
        for (int j = 0; j < 4; ++j) {
            const int gcol = bn + nt * 128 + wn + j * 16 + fr;
            float s = 0.f, q = 0.f;
            if (gcol < Nout) {
#pragma unroll
                for (int i = 0; i < 4; ++i) {
#pragma unroll
                    for (int rg = 0; rg < 4; ++rg) {
                        const float v = acc[nt][i][j][rg] * outScale;
                        C[(size_t)(bm + wm + i * 16 + quad * 4 + rg) * Nout + gcol] = v;
                        s += v;
                        q += v * v;
                    }
                }
            }
            s += __shfl_xor(s, 16); s += __shfl_xor(s, 32);
            q += __shfl_xor(q, 16); q += __shfl_xor(q, 32);
            if (quad == 0 && gcol < Nout) {
                atomicAdd(&s_out[gcol], s);
                atomicAdd(&q_out[gcol], q);
            }
        }
    }
}

// ---------------------------------------------------------------------------
// x[M x 700] fp32 -> A1[M x 1408] fp16: [hi(32x) | lo], zero-padded 700->704.
// One block per row; float4 reads, f16x4 writes.
// ---------------------------------------------------------------------------
__global__ __launch_bounds__(192) void split_x(const float* __restrict__ x,
                                               f16_t* __restrict__ A1) {
    const int m = blockIdx.x;
    const int t = threadIdx.x;
    if (t >= 176) return;
    const int k4 = t * 4;
    float4 v = make_float4(0.f, 0.f, 0.f, 0.f);
    if (k4 < Jn) v = *(const float4*)(x + (size_t)m * Jn + k4);
    f16x4 hv, lv;
    const float* pv = &v.x;
#pragma unroll
    for (int q = 0; q < 4; ++q) {
        const float f = pv[q] * 32.f;
        const f16_t h = (f16_t)f;
        hv[q] = h;
        lv[q] = (f16_t)(f - (float)h);
    }
    *(f16x4*)&A1[(size_t)m * (2 * Jp) + k4] = hv;
    *(f16x4*)&A1[(size_t)m * (2 * Jp) + Jp + k4] = lv;
}

// ---------------------------------------------------------------------------
// W[N x K] fp32 -> Wo[NP x 2*KP] fp16 [hi(scale*W) | lo], zero pad rows/cols.
// ---------------------------------------------------------------------------
__global__ __launch_bounds__(256) void split_w(const float* __restrict__ Wsrc,
                                               f16_t* __restrict__ Wo,
                                               int N, int K, int KP, int NP, float scale) {
    const int idx = blockIdx.x * 256 + threadIdx.x;
    if (idx >= NP * KP) return;
    const int n = idx / KP, k = idx % KP;
    const float f = (n < N && k < K) ? Wsrc[(size_t)n * K + k] * scale : 0.f;
    const f16_t hi = (f16_t)f;
    const f16_t lo = (f16_t)(f - (float)hi);
    Wo[(size_t)n * (2 * KP) + k] = hi;
    Wo[(size_t)n * (2 * KP) + KP + k] = lo;
}

// ---------------------------------------------------------------------------
// LIF scan: BN-normalize + sequential membrane update + spike (exact f16 out).
// ---------------------------------------------------------------------------
__global__ __launch_bounds__(256) void lif_scan(const float* __restrict__ X,
                                                f16_t* __restrict__ S_out,
                                                const float* __restrict__ sums,
                                                const float* __restrict__ sumsq,
                                                const float* __restrict__ beta_raw,
                                                const float* __restrict__ gamma,
                                                const float* __restrict__ bias,
                                                int B, int T, int N) {
    const int gid = blockIdx.x * blockDim.x + threadIdx.x;
    if (gid >= B * N) return;
    const int b = gid / N;
    const int i = gid % N;

    const float invM = 1.f / (float)(B * T);
    const float mean = sums[i] * invM;
    const float var = sumsq[i] * invM - mean * mean;
    const float inv = rsqrtf(var + 1e-5f);
    const float g = gamma[i] * inv;
    const float bi = bias[i] - mean * g;
    const float beta = 1.f / (1.f + expf(-beta_raw[i]));
    const float omb = 1.f - beta;

    const float* xp = X + (size_t)b * T * N + i;
    f16_t* sp = S_out + (size_t)b * T * N + i;

    float U = 0.f, Sp = 0.f;
#pragma unroll 8
    for (int t = 0; t < T; ++t) {
        const float xt = xp[(size_t)t * N] * g + bi;
        U = beta * (U - Sp) + omb * xt;
        Sp = (U > 1.0f) ? 1.0f : 0.0f;
        sp[(size_t)t * N] = (f16_t)Sp;
    }
}

// ---------------------------------------------------------------------------
// Readout: BN + linear EMA scan + softmax over 20 classes + sum over T.
// ---------------------------------------------------------------------------
__global__ __launch_bounds__(256) void readout_kernel(const float* __restrict__ A,
                                                      const float* __restrict__ sums,
                                                      const float* __restrict__ sumsq,
                                                      const float* __restrict__ beta_raw,
                                                      const float* __restrict__ gamma,
                                                      const float* __restrict__ bias,
                                                      float* __restrict__ out) {
    __shared__ float xs[Tn * On];
    __shared__ float gsh[On], bsh[On], betash[On];
    __shared__ float red[4][On];

    const int b = blockIdx.x;
    const int tid = threadIdx.x;

    if (tid < On) {
        const float invM = 1.f / (float)Mn;
        const float mean = sums[tid] * invM;
        const float var = sumsq[tid] * invM - mean * mean;
        const float inv = rsqrtf(var + 1e-5f);
        const float g = gamma[tid] * inv;
        gsh[tid] = g;
        bsh[tid] = bias[tid] - mean * g;
        betash[tid] = 1.f / (1.f + expf(-beta_raw[tid]));
    }
    __syncthreads();

    const float* Ab = A + (size_t)b * Tn * On;
    for (int idx = tid; idx < Tn * On; idx += 256) {
        const int o = idx % On;
        xs[idx] = Ab[idx] * gsh[o] + bsh[o];
    }
    __syncthreads();

    if (tid < On) {
        const float beta = betash[tid], omb = 1.f - beta;
        float U = 0.f;
        for (int t = 0; t < Tn; ++t) {
            U = beta * U + omb * xs[t * On + tid];
            xs[t * On + tid] = U;
        }
    }
    __syncthreads();

    float part[On];
#pragma unroll
    for (int o = 0; o < On; ++o) part[o] = 0.f;

    for (int t = tid; t < Tn; t += 256) {
        float v[On];
        float m = -1e30f;
#pragma unroll
        for (int o = 0; o < On; ++o) {
            v[o] = xs[t * On + o];
            m = fmaxf(m, v[o]);
        }
        float s = 0.f;
#pragma unroll
        for (int o = 0; o < On; ++o) {
            v[o] = expf(v[o] - m);
            s += v[o];
        }
        const float rs = 1.f / s;
#pragma unroll
        for (int o = 0; o < On; ++o) part[o] += v[o] * rs;
    }

#pragma unroll
    for (int o = 0; o < On; ++o) {
#pragma unroll
        for (int off = 32; off > 0; off >>= 1) part[o] += __shfl_down(part[o], off);
    }
    const int lane = tid & 63, wid = tid >> 6;
    if (lane == 0) {
#pragma unroll
        for (int o = 0; o < On; ++o) red[wid][o] = part[o];
    }
    __syncthreads();
    if (tid < On) out[b * On + tid] = red[0][tid] + red[1][tid] + red[2][tid] + red[3][tid];
}

// ---------------------------------------------------------------------------
extern "C" void kernel_launch(void* const* d_in, const int* in_sizes, int n_in,
                              void* d_out, int out_size, void* d_ws, size_t ws_size,
                              hipStream_t stream) {
    const float* x   = (const float*)d_in[0];
    const float* W1  = (const float*)d_in[1];
    const float* be1 = (const float*)d_in[2];
    const float* g1  = (const float*)d_in[3];
    const float* b1  = (const float*)d_in[4];
    const float* W2  = (const float*)d_in[5];
    const float* be2 = (const float*)d_in[6];
    const float* b2g = (const float*)d_in[7];
    const float* b2  = (const float*)d_in[8];
    const float* Wr  = (const float*)d_in[9];
    const float* ber = (const float*)d_in[10];
    const float* gr  = (const float*)d_in[11];
    const float* br  = (const float*)d_in[12];
    float* out = (float*)d_out;

    char* ws = (char*)d_ws;
    // A1 region (184.5 MB) is dead after GEMM1; bufS (67 MB) reuses it.
    const size_t a1Bytes   = (size_t)Mn * (2 * Jp) * sizeof(f16_t);   // 184.5 MB
    const size_t bufCBytes = (size_t)Mn * Hn * sizeof(float);         // 134 MB
    f16_t* A1   = (f16_t*)ws;
    f16_t* bufS = (f16_t*)ws;                         // overlaps A1 (sequenced)
    float* bufC = (float*)(ws + a1Bytes);
    char*  p    = ws + a1Bytes + bufCBytes;
    float* bufR = (float*)p;              p += (size_t)Mn * On * sizeof(float);
    f16_t* W1s  = (f16_t*)p;              p += (size_t)Hn * (2 * Jp) * sizeof(f16_t);
    f16_t* W2s  = (f16_t*)p;              p += (size_t)Hn * (2 * Hn) * sizeof(f16_t);
    f16_t* Wrs  = (f16_t*)p;              p += (size_t)128 * (2 * Hn) * sizeof(f16_t);
    float* stats = (float*)p;
    float* s1 = stats;       float* q1 = s1 + Hn;
    float* s2 = q1 + Hn;     float* q2 = s2 + Hn;
    float* s3 = q2 + Hn;     float* q3 = s3 + 32;

    hipMemsetAsync(stats, 0, (4 * Hn + 64) * sizeof(float), stream);

    // Pre-split inputs/weights into folded hi|lo fp16 planes (scaled).
    split_x<<<Mn, 192, 0, stream>>>(x, A1);
    split_w<<<(Hn * Jp + 255) / 256, 256, 0, stream>>>(W1, W1s, Hn, Jn, Jp, Hn, 64.f);
    split_w<<<(Hn * Hn + 255) / 256, 256, 0, stream>>>(W2, W2s, Hn, Hn, Hn, Hn, 64.f);
    split_w<<<(128 * Hn + 255) / 256, 256, 0, stream>>>(Wr, Wrs, On, Hn, Hn, 128, 64.f);

    // Layer 1: [xhi|xlo][M x 1408] * [W1hi|W1lo][512 x 1408]^T  (scale 2^-11)
    gemm_strip<2><<<dim3(2, Mn / 128), 256, 0, stream>>>(A1, W1s, bufC, s1, q1,
        2 * Jp, Jp, 2 * Jp, Jp, Jp / 32, Hn, 1.f / 2048.f);
    lif_scan<<<(Bn * Hn) / 256, 256, 0, stream>>>(bufC, bufS, s1, q1, be1, g1, b1, Bn, Tn, Hn);

    // Layer 2: S[M x 512] * [W2hi|W2lo][512 x 1024]^T  (scale 2^-6)
    gemm_strip<2><<<dim3(2, Mn / 128), 256, 0, stream>>>(bufS, W2s, bufC, s2, q2,
        Hn, 0, 2 * Hn, Hn, Hn / 32, Hn, 1.f / 64.f);
    lif_scan<<<(Bn * Hn) / 256, 256, 0, stream>>>(bufC, bufS, s2, q2, be2, b2g, b2, Bn, Tn, Hn);

    // Readout: S[M x 512] * [Wrhi|Wrlo][128 x 1024]^T -> [M x 20]  (scale 2^-6)
    gemm_strip<1><<<dim3(1, Mn / 128), 256, 0, stream>>>(bufS, Wrs, bufR, s3, q3,
        Hn, 0, 2 * Hn, Hn, Hn / 32, On, 1.f / 64.f);
    readout_kernel<<<Bn, 256, 0, stream>>>(bufR, s3, q3, ber, gr, br, out);
}